// Round 14
// baseline (44.795 us; speedup 1.0000x reference)
//
#include <hip/hip_runtime.h>
#include <hip/hip_bf16.h>

#define B_SZ 4096
#define IN_D 256
#define OUT_D 256
#define NC 8

#define BM 64
#define BN 32
#define SSTEPS 16           // per wave: K = 2048/4 = 512 -> 16 steps of K=32

using f32x4 = __attribute__((ext_vector_type(4))) float;
using s16x8 = __attribute__((ext_vector_type(8))) short;

__device__ __forceinline__ unsigned short f2bf(float f) {
    union { float f; unsigned int u; } v; v.f = f;
    return (unsigned short)((v.u + 0x7fffu + ((v.u >> 16) & 1u)) >> 16);  // RNE
}

__device__ __forceinline__ float fast_tanh(float x) {
    float e = __expf(2.0f * x);   // saturates correctly at +-inf
    return 1.0f - 2.0f / (e + 1.0f);
}

// ---------------------------------------------------------------------------
// Fused prep, 512 blocks (UNCHANGED from R10).
// Blocks [0,256): 64b x 64i tanh tile -> tTI interleaved:
//   tTI[i*B_SZ + G*64 + lr*4 + f] = tanh(x[G*64 + f*16 + lr, i])
// Blocks [256,512): W[(i*OUT+o)*8+j] bf16 blocked, i = bid-256.
// ---------------------------------------------------------------------------
__global__ __launch_bounds__(256) void kan_prep(
    const float* __restrict__ x, const float* __restrict__ coefs,
    const float* __restrict__ alpha_at, const float* __restrict__ resid_scale,
    const float* __restrict__ spline_scale,
    float* __restrict__ tTI, unsigned short* __restrict__ Wg)
{
    const int tid = threadIdx.x;
    const int bid = blockIdx.x;

    if (bid < 256) {                     // ---- tanh + interleaved transpose
        __shared__ float tt[64][68];
        const int b0 = (bid & 63) * 64;  // G = bid & 63
        const int i0 = (bid >> 6) * 64;
        #pragma unroll
        for (int it = 0; it < 16; it++) {
            int e = it * 256 + tid;
            int r = e >> 6, c = e & 63;
            tt[r][c] = fast_tanh(x[(size_t)(b0 + r) * IN_D + i0 + c]);
        }
        __syncthreads();
        const int lr = tid & 15;
        const int ib = tid >> 4;         // 0..15
        #pragma unroll
        for (int k = 0; k < 4; k++) {
            int i = ib + k * 16;         // 0..63
            f32x4 v = { tt[lr][i], tt[lr + 16][i], tt[lr + 32][i], tt[lr + 48][i] };
            *(f32x4*)(tTI + (size_t)(i0 + i) * B_SZ + b0 + lr * 4) = v;
        }
        return;
    }

    // ---- W prep (one feature i per block)
    const int i = bid - 256;
    const int o = tid;

    float al = tanhf(alpha_at[0]);
    float mono[NC][NC];
    #pragma unroll
    for (int a = 0; a < NC; a++)
        #pragma unroll
        for (int b = 0; b < NC; b++) mono[a][b] = 0.f;
    mono[0][0] = 1.f;
    mono[1][1] = al + 1.f;
    #pragma unroll
    for (int n = 2; n < NC; n++) {
        float fn = (float)n;
        float c  = 2.f * fn + 2.f * al;
        float An = 2.f * fn * (fn + 2.f * al) * (c - 2.f);
        float Bn = (c - 1.f) * c * (c - 2.f);
        float Cn = 2.f * (fn + al - 1.f) * (fn + al - 1.f) * c;
        #pragma unroll
        for (int j = 0; j < NC; j++) {
            float tm = (j > 0 ? mono[n - 1][j - 1] : 0.f);
            mono[n][j] = (Bn * tm - Cn * mono[n - 2][j]) / An;
        }
    }

    float cf[NC];
    const float* cp = coefs + ((size_t)i * OUT_D + o) * NC;
    #pragma unroll
    for (int c = 0; c < NC; c++) cf[c] = cp[c];
    float ss = spline_scale[i * OUT_D + o];
    float rs = resid_scale[i];

    unsigned short w8[NC];
    #pragma unroll
    for (int j = 0; j < NC; j++) {
        float wv = 0.f;
        #pragma unroll
        for (int c = 0; c < NC; c++) wv += mono[c][j] * cf[c];
        wv *= ss * (1.0f / IN_D);
        if (j == 1) wv += rs * (1.0f / IN_D);
        w8[j] = f2bf(wv);
    }
    uint4 pk;
    unsigned int* pu = (unsigned int*)&pk;
    #pragma unroll
    for (int h = 0; h < 4; h++)
        pu[h] = (unsigned int)w8[2 * h] | ((unsigned int)w8[2 * h + 1] << 16);
    *(uint4*)(Wg + ((size_t)i * OUT_D + o) * NC) = pk;
}

// ---------------------------------------------------------------------------
// Barrier-free GEMM (UNCHANGED from R10). Block = 64x32 tile, 4 waves =
// 4-way K-split, 16 steps fully unrolled, coalesced float4/uint4 loads,
// power chains in registers, LDS reduce at the end. 512 blocks.
// ---------------------------------------------------------------------------
__global__ __launch_bounds__(256) void kan_gemm(
    const float* __restrict__ tTI, const unsigned short* __restrict__ Wg,
    float* __restrict__ out)
{
    __shared__ __align__(16) float lbuf[3][64 * 36];   // 27.6 KB

    const int tid  = threadIdx.x;
    const int lane = tid & 63;
    const int kg   = tid >> 6;          // wave = K-split index 0..3
    const int lr   = lane & 15;
    const int il   = lane >> 4;         // 0..3: feature-within-step

    // XCD-aware bijective swizzle (512 % 8 == 0); 64 mblk x 8 nblk
    const int bid  = blockIdx.x;
    const int swz  = (bid & 7) * 64 + (bid >> 3);
    const int mblk = swz >> 3, nblk = swz & 7;
    const int bm = mblk * BM, bn = nblk * BN;

    f32x4 acc[4][2];
    #pragma unroll
    for (int f = 0; f < 4; f++)
        #pragma unroll
        for (int g = 0; g < 2; g++)
            acc[f][g] = (f32x4){0.f, 0.f, 0.f, 0.f};

    const float* tbase = tTI + bm + lr * 4;                     // + i0*B_SZ per step
    const unsigned short* wbase = Wg + ((size_t)bn + lr) * NC;  // + i0*OUT*NC

    #pragma unroll
    for (int s = 0; s < SSTEPS; ++s) {
        const int i0 = kg * 64 + s * 4 + il;     // this lane's feature index

        // W fragments: 16B/lane direct from global (L2-resident)
        uint4 bw[2];
        #pragma unroll
        for (int g = 0; g < 2; g++)
            bw[g] = *(const uint4*)(wbase + ((size_t)i0 * OUT_D + g * 16) * NC);

        // t for f=0..3 in ONE float4
        f32x4 tv = *(const f32x4*)(tbase + (size_t)i0 * B_SZ);

        // A fragments: power chains in registers
        s16x8 af[4];
        #pragma unroll
        for (int f = 0; f < 4; f++) {
            float t = tv[f];
            float p2 = t * t, p3 = p2 * t, p4 = p3 * t;
            float p5 = p4 * t, p6 = p5 * t, p7 = p6 * t;
            __hip_bfloat162 h0 = __float22bfloat162_rn(make_float2(1.0f, t));
            __hip_bfloat162 h1 = __float22bfloat162_rn(make_float2(p2, p3));
            __hip_bfloat162 h2 = __float22bfloat162_rn(make_float2(p4, p5));
            __hip_bfloat162 h3 = __float22bfloat162_rn(make_float2(p6, p7));
            uint4 pk;
            pk.x = *(unsigned int*)&h0;
            pk.y = *(unsigned int*)&h1;
            pk.z = *(unsigned int*)&h2;
            pk.w = *(unsigned int*)&h3;
            af[f] = *(s16x8*)&pk;
        }

        #pragma unroll
        for (int f = 0; f < 4; f++)
            #pragma unroll
            for (int g = 0; g < 2; g++)
                acc[f][g] = __builtin_amdgcn_mfma_f32_16x16x32_bf16(
                    af[f], *(s16x8*)&bw[g], acc[f][g], 0, 0, 0);
    }

    // ---- K-split reduction: waves 1..3 dump, wave 0 accumulates + stores
    if (kg > 0) {
        float* dst = &lbuf[kg - 1][lane * 36];
        #pragma unroll
        for (int f = 0; f < 4; f++)
            #pragma unroll
            for (int g = 0; g < 2; g++)
                *(f32x4*)(dst + f * 8 + g * 4) = acc[f][g];
    }
    __syncthreads();
    if (kg == 0) {
        #pragma unroll
        for (int r = 0; r < 3; r++) {
            const float* src = &lbuf[r][lane * 36];
            #pragma unroll
            for (int f = 0; f < 4; f++)
                #pragma unroll
                for (int g = 0; g < 2; g++)
                    acc[f][g] += *(const f32x4*)(src + f * 8 + g * 4);
        }
        // C/D layout: col = lane&15, row = (lane>>4)*4 + j
        #pragma unroll
        for (int f = 0; f < 4; f++)
            #pragma unroll
            for (int g = 0; g < 2; g++)
                #pragma unroll
                for (int j = 0; j < 4; j++) {
                    int r = bm + f * 16 + il * 4 + j;
                    int c = bn + g * 16 + lr;
                    out[(size_t)r * OUT_D + c] = acc[f][g][j];
                }
    }
}

extern "C" void kernel_launch(void* const* d_in, const int* in_sizes, int n_in,
                              void* d_out, int out_size, void* d_ws, size_t ws_size,
                              hipStream_t stream) {
    const float* x     = (const float*)d_in[0];
    const float* coefs = (const float*)d_in[1];
    const float* alpha = (const float*)d_in[2];
    const float* rs    = (const float*)d_in[3];
    const float* ss    = (const float*)d_in[4];
    float* out = (float*)d_out;

    unsigned short* Wg = (unsigned short*)d_ws;              // 1 MB
    float* tTI = (float*)((char*)d_ws + (1 << 20));          // 4 MB

    // MEASUREMENT ROUND: 3x each (idempotent; identical outputs).
    // dur = O + 3W vs R10's O + W = 19.93  =>  W = (dur - 19.93)/2.
    const dim3 gp(512), gg((B_SZ / BM) * (OUT_D / BN));
    kan_prep<<<gp, dim3(256), 0, stream>>>(x, coefs, alpha, rs, ss, tTI, Wg);
    kan_prep<<<gp, dim3(256), 0, stream>>>(x, coefs, alpha, rs, ss, tTI, Wg);
    kan_prep<<<gp, dim3(256), 0, stream>>>(x, coefs, alpha, rs, ss, tTI, Wg);
    kan_gemm<<<gg, dim3(256), 0, stream>>>(tTI, Wg, out);
    kan_gemm<<<gg, dim3(256), 0, stream>>>(tTI, Wg, out);
    kan_gemm<<<gg, dim3(256), 0, stream>>>(tTI, Wg, out);
}

// Round 15
// 26.163 us; speedup vs baseline: 1.7122x; 1.7122x over previous
//
#include <hip/hip_runtime.h>
#include <hip/hip_bf16.h>

#define B_SZ 4096
#define IN_D 256
#define OUT_D 256
#define NC 8

#define BM 64
#define BN 32
#define SSTEPS 16           // per wave: K-slice = 64 i's = 16 steps x 4 i
#define TS 65               // t-panel LDS stride (floats) per i

using f32x4 = __attribute__((ext_vector_type(4))) float;
using s16x8 = __attribute__((ext_vector_type(8))) short;

__device__ __forceinline__ float fast_tanh(float x) {
    float e = __expf(2.0f * x);   // saturates correctly at +-inf
    return 1.0f - 2.0f / (e + 1.0f);
}

__device__ __forceinline__ unsigned int pack2(float a, float b) {
    __hip_bfloat162 h = __float22bfloat162_rn(make_float2(a, b));
    return *(unsigned int*)&h;
}

// ---------------------------------------------------------------------------
// SINGLE-NODE fused KAN layer (R13 minus its x-gather flaw).
// Math (verified R12/R13): out[b,o] = sum_{i,c} bf16(P_c(tanh x[b,i]))*W'[i,o,c]
//   W'[i,o,c] = ss[i,o]*cf[i,o,c]/256 + (c==1 ? rs[i]/(256*(alpha+1)) : 0)
// Block: 64x32 tile, 256 threads = 4 waves = 4-way K-split, 512 blocks (2/CU).
// Phase 1: t-panel tanh(x[bm..bm+63][0..255]) -> LDS, COALESCED x reads
//          (thread = column i, 64 rows; interleaved word (r&15)*4+(r>>4);
//          stride 65: write banks (i+w)%32 conflict-free, reads 2-way=free).
// Phase 2: 16 fully-unrolled steps; A = P_c chains from LDS t (4 x ds_read_b32);
//          B = W' in-register from coalesced L2-resident coef loads; 8 MFMA.
// Phase 3: LDS K-split reduce (overlays the t-panel), wave 0 stores.
// ---------------------------------------------------------------------------
__global__ __launch_bounds__(256) void kan_fused(
    const float* __restrict__ x, const float* __restrict__ coefs,
    const float* __restrict__ alpha_at, const float* __restrict__ resid_scale,
    const float* __restrict__ spline_scale, float* __restrict__ out)
{
    __shared__ __align__(16) float tt[IN_D * TS];   // 66.6 KB; reused as lbuf

    const int tid  = threadIdx.x;
    const int lane = tid & 63;
    const int kg   = tid >> 6;      // wave = K-split index 0..3
    const int lr   = lane & 15;
    const int il   = lane >> 4;     // 0..3

    // XCD-aware bijective swizzle (512 % 8 == 0); 64 mblk x 8 nblk
    const int bid  = blockIdx.x;
    const int swz  = (bid & 7) * 64 + (bid >> 3);
    const int mblk = swz >> 3, nblk = swz & 7;
    const int bm = mblk * BM, bn = nblk * BN;

    // alpha-derived wave-uniform constants
    const float al = tanhf(alpha_at[0]);
    const float h  = al + 1.0f;
    float bc[8], cc[8];
    bc[0] = bc[1] = cc[0] = cc[1] = 0.f;
    #pragma unroll
    for (int n = 2; n < 8; n++) {
        float fn = (float)n;
        float c  = 2.f * fn + 2.f * al;
        float An = 2.f * fn * (fn + 2.f * al) * (c - 2.f);
        bc[n] = (c - 1.f) * c * (c - 2.f) / An;
        cc[n] = 2.f * (fn + al - 1.f) * (fn + al - 1.f) * c / An;
    }
    const float inv256 = 1.0f / 256.0f;
    const float r1 = inv256 / h;

    // ---- Phase 1: t-panel -> LDS (coalesced x reads) --------------------
    {
        const float* xp = x + (size_t)bm * IN_D + tid;   // column i = tid
        float* col = tt + tid * TS;
        #pragma unroll 8
        for (int r = 0; r < 64; r++) {
            float t = fast_tanh(xp[(size_t)r * IN_D]);
            col[(r & 15) * 4 + (r >> 4)] = t;            // word = lr*4 + f
        }
    }
    __syncthreads();

    // ---- Phase 2: main loop ---------------------------------------------
    f32x4 acc[4][2];
    #pragma unroll
    for (int f = 0; f < 4; f++)
        #pragma unroll
        for (int g = 0; g < 2; g++)
            acc[f][g] = (f32x4){0.f, 0.f, 0.f, 0.f};

    #pragma unroll
    for (int s = 0; s < SSTEPS; ++s) {
        const int i = kg * 64 + s * 4 + il;   // this lane's feature index

        // ---- B fragments: W' in-register (coalesced, L2-resident) ----
        const float* cp = coefs + ((size_t)i * OUT_D + bn + lr) * NC;
        f32x4 c0a = *(const f32x4*)(cp);
        f32x4 c0b = *(const f32x4*)(cp + 4);
        f32x4 c1a = *(const f32x4*)(cp + 16 * NC);
        f32x4 c1b = *(const f32x4*)(cp + 16 * NC + 4);
        float ss0 = spline_scale[i * OUT_D + bn + lr] * inv256;
        float ss1 = spline_scale[i * OUT_D + bn + 16 + lr] * inv256;
        float rsf = resid_scale[i] * r1;

        uint4 b0, b1;
        b0.x = pack2(ss0 * c0a[0], __builtin_fmaf(ss0, c0a[1], rsf));
        b0.y = pack2(ss0 * c0a[2], ss0 * c0a[3]);
        b0.z = pack2(ss0 * c0b[0], ss0 * c0b[1]);
        b0.w = pack2(ss0 * c0b[2], ss0 * c0b[3]);
        b1.x = pack2(ss1 * c1a[0], __builtin_fmaf(ss1, c1a[1], rsf));
        b1.y = pack2(ss1 * c1a[2], ss1 * c1a[3]);
        b1.z = pack2(ss1 * c1b[0], ss1 * c1b[1]);
        b1.w = pack2(ss1 * c1b[2], ss1 * c1b[3]);

        // ---- A fragments: t from LDS panel, P_c recurrence in regs ----
        const float* tp = tt + i * TS + lr * 4;          // words lr*4 + f
        s16x8 af[4];
        #pragma unroll
        for (int f = 0; f < 4; f++) {
            float t = tp[f];
            float P[8];
            P[0] = 1.0f;
            P[1] = __builtin_fmaf(h, t - 1.0f, h);
            #pragma unroll
            for (int n = 2; n < 8; n++)
                P[n] = __builtin_fmaf(bc[n], t * P[n - 1], -(cc[n] * P[n - 2]));
            uint4 pk;
            pk.x = pack2(P[0], P[1]);
            pk.y = pack2(P[2], P[3]);
            pk.z = pack2(P[4], P[5]);
            pk.w = pack2(P[6], P[7]);
            af[f] = *(s16x8*)&pk;
        }

        #pragma unroll
        for (int f = 0; f < 4; f++) {
            acc[f][0] = __builtin_amdgcn_mfma_f32_16x16x32_bf16(af[f], *(s16x8*)&b0, acc[f][0], 0, 0, 0);
            acc[f][1] = __builtin_amdgcn_mfma_f32_16x16x32_bf16(af[f], *(s16x8*)&b1, acc[f][1], 0, 0, 0);
        }
    }

    // ---- Phase 3: K-split reduction (overlays t-panel) ------------------
    __syncthreads();                      // everyone done reading tt
    float* lbuf = tt;
    if (kg > 0) {
        float* dst = lbuf + (kg - 1) * (64 * 36) + lane * 36;
        #pragma unroll
        for (int f = 0; f < 4; f++)
            #pragma unroll
            for (int g = 0; g < 2; g++)
                *(f32x4*)(dst + f * 8 + g * 4) = acc[f][g];
    }
    __syncthreads();
    if (kg == 0) {
        #pragma unroll
        for (int r = 0; r < 3; r++) {
            const float* src = lbuf + r * (64 * 36) + lane * 36;
            #pragma unroll
            for (int f = 0; f < 4; f++)
                #pragma unroll
                for (int g = 0; g < 2; g++)
                    acc[f][g] += *(const f32x4*)(src + f * 8 + g * 4);
        }
        // C/D layout: col = lane&15, row = (lane>>4)*4 + j
        #pragma unroll
        for (int f = 0; f < 4; f++)
            #pragma unroll
            for (int g = 0; g < 2; g++)
                #pragma unroll
                for (int j = 0; j < 4; j++) {
                    int r = bm + f * 16 + il * 4 + j;
                    int c = bn + g * 16 + lr;
                    out[(size_t)r * OUT_D + c] = acc[f][g][j];
                }
    }
}

extern "C" void kernel_launch(void* const* d_in, const int* in_sizes, int n_in,
                              void* d_out, int out_size, void* d_ws, size_t ws_size,
                              hipStream_t stream) {
    const float* x     = (const float*)d_in[0];
    const float* coefs = (const float*)d_in[1];
    const float* alpha = (const float*)d_in[2];
    const float* rs    = (const float*)d_in[3];
    const float* ss    = (const float*)d_in[4];
    float* out = (float*)d_out;

    kan_fused<<<dim3((B_SZ / BM) * (OUT_D / BN)), dim3(256), 0, stream>>>(
        x, coefs, alpha, rs, ss, out);
}

// Round 16
// 24.167 us; speedup vs baseline: 1.8536x; 1.0826x over previous
//
#include <hip/hip_runtime.h>
#include <hip/hip_bf16.h>

#define B_SZ 4096
#define IN_D 256
#define OUT_D 256
#define NC 8

#define BM 64
#define BN 32
#define SSTEPS 16           // per wave: K-slice = 64 i's = 16 steps x 4 i
#define TS 65               // t-panel LDS stride (floats) per column i

using f32x4 = __attribute__((ext_vector_type(4))) float;
using s16x8 = __attribute__((ext_vector_type(8))) short;

__device__ __forceinline__ unsigned short f2bf(float f) {
    union { float f; unsigned int u; } v; v.f = f;
    return (unsigned short)((v.u + 0x7fffu + ((v.u >> 16) & 1u)) >> 16);  // RNE
}

__device__ __forceinline__ float fast_tanh(float x) {
    float e = __expf(2.0f * x);   // saturates correctly at +-inf
    return 1.0f - 2.0f / (e + 1.0f);
}

// ---------------------------------------------------------------------------
// prep_w (R10's W branch, standalone): 256 blocks x 256 threads.
// W[(i*OUT+o)*8+j] = bf16((1/IN)*(ss[i,o]*sum_c mono[c][j]*cf[c]
//                           + (j==1 ? rs[i] : 0)))
// ---------------------------------------------------------------------------
__global__ __launch_bounds__(256) void prep_w(
    const float* __restrict__ coefs, const float* __restrict__ alpha_at,
    const float* __restrict__ resid_scale, const float* __restrict__ spline_scale,
    unsigned short* __restrict__ Wg)
{
    const int i = blockIdx.x;
    const int o = threadIdx.x;

    float al = tanhf(alpha_at[0]);
    float mono[NC][NC];
    #pragma unroll
    for (int a = 0; a < NC; a++)
        #pragma unroll
        for (int b = 0; b < NC; b++) mono[a][b] = 0.f;
    mono[0][0] = 1.f;
    mono[1][1] = al + 1.f;
    #pragma unroll
    for (int n = 2; n < NC; n++) {
        float fn = (float)n;
        float c  = 2.f * fn + 2.f * al;
        float An = 2.f * fn * (fn + 2.f * al) * (c - 2.f);
        float Bn = (c - 1.f) * c * (c - 2.f);
        float Cn = 2.f * (fn + al - 1.f) * (fn + al - 1.f) * c;
        #pragma unroll
        for (int j = 0; j < NC; j++) {
            float tm = (j > 0 ? mono[n - 1][j - 1] : 0.f);
            mono[n][j] = (Bn * tm - Cn * mono[n - 2][j]) / An;
        }
    }

    float cf[NC];
    const float* cp = coefs + ((size_t)i * OUT_D + o) * NC;
    #pragma unroll
    for (int c = 0; c < NC; c++) cf[c] = cp[c];
    float ss = spline_scale[i * OUT_D + o];
    float rs = resid_scale[i];

    unsigned short w8[NC];
    #pragma unroll
    for (int j = 0; j < NC; j++) {
        float wv = 0.f;
        #pragma unroll
        for (int c = 0; c < NC; c++) wv += mono[c][j] * cf[c];
        wv *= ss * (1.0f / IN_D);
        if (j == 1) wv += rs * (1.0f / IN_D);
        w8[j] = f2bf(wv);
    }
    uint4 pk;
    unsigned int* pu = (unsigned int*)&pk;
    #pragma unroll
    for (int h = 0; h < 4; h++)
        pu[h] = (unsigned int)w8[2 * h] | ((unsigned int)w8[2 * h + 1] << 16);
    *(uint4*)(Wg + ((size_t)i * OUT_D + o) * NC) = pk;
}

// ---------------------------------------------------------------------------
// GEMM with in-kernel coalesced t-panel (R15 phase-1 + R10 loop).
// Block = 64x32 tile, 256 threads = 4 waves = 4-way K-split, 512 blocks (2/CU).
// Phase 1: tanh(x[bm..bm+63][0..255]) -> LDS. Thread = column i (coalesced x
//   reads); word (r&15)*4 + (r>>4) in a TS=65 column -> main-loop read of
//   t(bm+f*16+lr, i0) is 4 scalar b32, banks (i0+4lr+f)%32 = 2-way = free.
// Phase 2: 16 fully-unrolled steps; per lane: 2 Wg uint4 (L2) + 4 LDS t +
//   power chains in registers + 8 MFMA. Zero barriers in the loop.
// Phase 3: K-split LDS reduce (overlays t-panel), wave 0 stores.
// ---------------------------------------------------------------------------
__global__ __launch_bounds__(256) void kan_gemm(
    const float* __restrict__ x, const unsigned short* __restrict__ Wg,
    float* __restrict__ out)
{
    __shared__ __align__(16) float tt[IN_D * TS];   // 66.6 KB; reused as lbuf

    const int tid  = threadIdx.x;
    const int lane = tid & 63;
    const int kg   = tid >> 6;          // wave = K-split index 0..3
    const int lr   = lane & 15;
    const int il   = lane >> 4;         // 0..3: feature-within-step

    // XCD-aware bijective swizzle (512 % 8 == 0); 64 mblk x 8 nblk
    const int bid  = blockIdx.x;
    const int swz  = (bid & 7) * 64 + (bid >> 3);
    const int mblk = swz >> 3, nblk = swz & 7;
    const int bm = mblk * BM, bn = nblk * BN;

    // ---- Phase 1: t-panel -> LDS (coalesced x reads; verified R15) ----
    {
        const float* xp = x + (size_t)bm * IN_D + tid;   // column i = tid
        float* col = tt + tid * TS;
        #pragma unroll 8
        for (int r = 0; r < 64; r++) {
            float t = fast_tanh(xp[(size_t)r * IN_D]);
            col[(r & 15) * 4 + (r >> 4)] = t;
        }
    }
    __syncthreads();

    // ---- Phase 2: R10 main loop (t from LDS) ---------------------------
    f32x4 acc[4][2];
    #pragma unroll
    for (int f = 0; f < 4; f++)
        #pragma unroll
        for (int g = 0; g < 2; g++)
            acc[f][g] = (f32x4){0.f, 0.f, 0.f, 0.f};

    const unsigned short* wbase = Wg + ((size_t)bn + lr) * NC;  // + i0*OUT*NC

    #pragma unroll
    for (int s = 0; s < SSTEPS; ++s) {
        const int i0 = kg * 64 + s * 4 + il;     // this lane's feature index

        // W fragments: 16B/lane direct from global (L2-resident)
        uint4 bw[2];
        #pragma unroll
        for (int g = 0; g < 2; g++)
            bw[g] = *(const uint4*)(wbase + ((size_t)i0 * OUT_D + g * 16) * NC);

        // t for f=0..3 from LDS (scalar b32, conflict-free)
        const float* tp = tt + i0 * TS + lr * 4;

        // A fragments: power chains in registers
        s16x8 af[4];
        #pragma unroll
        for (int f = 0; f < 4; f++) {
            float t = tp[f];
            float p2 = t * t, p3 = p2 * t, p4 = p3 * t;
            float p5 = p4 * t, p6 = p5 * t, p7 = p6 * t;
            __hip_bfloat162 h0 = __float22bfloat162_rn(make_float2(1.0f, t));
            __hip_bfloat162 h1 = __float22bfloat162_rn(make_float2(p2, p3));
            __hip_bfloat162 h2 = __float22bfloat162_rn(make_float2(p4, p5));
            __hip_bfloat162 h3 = __float22bfloat162_rn(make_float2(p6, p7));
            uint4 pk;
            pk.x = *(unsigned int*)&h0;
            pk.y = *(unsigned int*)&h1;
            pk.z = *(unsigned int*)&h2;
            pk.w = *(unsigned int*)&h3;
            af[f] = *(s16x8*)&pk;
        }

        #pragma unroll
        for (int f = 0; f < 4; f++)
            #pragma unroll
            for (int g = 0; g < 2; g++)
                acc[f][g] = __builtin_amdgcn_mfma_f32_16x16x32_bf16(
                    af[f], *(s16x8*)&bw[g], acc[f][g], 0, 0, 0);
    }

    // ---- Phase 3: K-split reduction (overlays t-panel) ------------------
    __syncthreads();                      // everyone done reading tt
    float* lbuf = tt;
    if (kg > 0) {
        float* dst = lbuf + (kg - 1) * (64 * 36) + lane * 36;
        #pragma unroll
        for (int f = 0; f < 4; f++)
            #pragma unroll
            for (int g = 0; g < 2; g++)
                *(f32x4*)(dst + f * 8 + g * 4) = acc[f][g];
    }
    __syncthreads();
    if (kg == 0) {
        #pragma unroll
        for (int r = 0; r < 3; r++) {
            const float* src = lbuf + r * (64 * 36) + lane * 36;
            #pragma unroll
            for (int f = 0; f < 4; f++)
                #pragma unroll
                for (int g = 0; g < 2; g++)
                    acc[f][g] += *(const f32x4*)(src + f * 8 + g * 4);
        }
        // C/D layout: col = lane&15, row = (lane>>4)*4 + j
        #pragma unroll
        for (int f = 0; f < 4; f++)
            #pragma unroll
            for (int g = 0; g < 2; g++)
                #pragma unroll
                for (int j = 0; j < 4; j++) {
                    int r = bm + f * 16 + il * 4 + j;
                    int c = bn + g * 16 + lr;
                    out[(size_t)r * OUT_D + c] = acc[f][g][j];
                }
    }
}

extern "C" void kernel_launch(void* const* d_in, const int* in_sizes, int n_in,
                              void* d_out, int out_size, void* d_ws, size_t ws_size,
                              hipStream_t stream) {
    const float* x     = (const float*)d_in[0];
    const float* coefs = (const float*)d_in[1];
    const float* alpha = (const float*)d_in[2];
    const float* rs    = (const float*)d_in[3];
    const float* ss    = (const float*)d_in[4];
    float* out = (float*)d_out;

    unsigned short* Wg = (unsigned short*)d_ws;   // 1 MB

    prep_w<<<dim3(IN_D), dim3(OUT_D), 0, stream>>>(coefs, alpha, rs, ss, Wg);
    kan_gemm<<<dim3((B_SZ / BM) * (OUT_D / BN)), dim3(256), 0, stream>>>(x, Wg, out);
}

// Round 17
// 20.123 us; speedup vs baseline: 2.2260x; 1.2009x over previous
//
#include <hip/hip_runtime.h>
#include <hip/hip_bf16.h>

#define B_SZ 4096
#define IN_D 256
#define OUT_D 256
#define NC 8

#define BM 128
#define BN 32
#define SSTEPS 16           // per wave: K = 2048/4 = 512 -> 16 steps of K=32

using f32x4 = __attribute__((ext_vector_type(4))) float;
using s16x8 = __attribute__((ext_vector_type(8))) short;

__device__ __forceinline__ unsigned short f2bf(float f) {
    union { float f; unsigned int u; } v; v.f = f;
    return (unsigned short)((v.u + 0x7fffu + ((v.u >> 16) & 1u)) >> 16);  // RNE
}

__device__ __forceinline__ float fast_tanh(float x) {
    float e = __expf(2.0f * x);   // saturates correctly at +-inf
    return 1.0f - 2.0f / (e + 1.0f);
}

// ---------------------------------------------------------------------------
// Fused prep, 512 blocks (UNCHANGED from R10, proven).
// Blocks [0,256): 64b x 64i tanh tile -> tTI interleaved:
//   tTI[i*B_SZ + G*64 + lr*4 + f] = tanh(x[G*64 + f*16 + lr, i])
// Blocks [256,512): W[(i*OUT+o)*8+j] bf16 blocked, i = bid-256.
// ---------------------------------------------------------------------------
__global__ __launch_bounds__(256) void kan_prep(
    const float* __restrict__ x, const float* __restrict__ coefs,
    const float* __restrict__ alpha_at, const float* __restrict__ resid_scale,
    const float* __restrict__ spline_scale,
    float* __restrict__ tTI, unsigned short* __restrict__ Wg)
{
    const int tid = threadIdx.x;
    const int bid = blockIdx.x;

    if (bid < 256) {                     // ---- tanh + interleaved transpose
        __shared__ float tt[64][68];
        const int b0 = (bid & 63) * 64;  // G = bid & 63
        const int i0 = (bid >> 6) * 64;
        #pragma unroll
        for (int it = 0; it < 16; it++) {
            int e = it * 256 + tid;
            int r = e >> 6, c = e & 63;
            tt[r][c] = fast_tanh(x[(size_t)(b0 + r) * IN_D + i0 + c]);
        }
        __syncthreads();
        const int lr = tid & 15;
        const int ib = tid >> 4;         // 0..15
        #pragma unroll
        for (int k = 0; k < 4; k++) {
            int i = ib + k * 16;         // 0..63
            f32x4 v = { tt[lr][i], tt[lr + 16][i], tt[lr + 32][i], tt[lr + 48][i] };
            *(f32x4*)(tTI + (size_t)(i0 + i) * B_SZ + b0 + lr * 4) = v;
        }
        return;
    }

    // ---- W prep (one feature i per block)
    const int i = bid - 256;
    const int o = tid;

    float al = tanhf(alpha_at[0]);
    float mono[NC][NC];
    #pragma unroll
    for (int a = 0; a < NC; a++)
        #pragma unroll
        for (int b = 0; b < NC; b++) mono[a][b] = 0.f;
    mono[0][0] = 1.f;
    mono[1][1] = al + 1.f;
    #pragma unroll
    for (int n = 2; n < NC; n++) {
        float fn = (float)n;
        float c  = 2.f * fn + 2.f * al;
        float An = 2.f * fn * (fn + 2.f * al) * (c - 2.f);
        float Bn = (c - 1.f) * c * (c - 2.f);
        float Cn = 2.f * (fn + al - 1.f) * (fn + al - 1.f) * c;
        #pragma unroll
        for (int j = 0; j < NC; j++) {
            float tm = (j > 0 ? mono[n - 1][j - 1] : 0.f);
            mono[n][j] = (Bn * tm - Cn * mono[n - 2][j]) / An;
        }
    }

    float cf[NC];
    const float* cp = coefs + ((size_t)i * OUT_D + o) * NC;
    #pragma unroll
    for (int c = 0; c < NC; c++) cf[c] = cp[c];
    float ss = spline_scale[i * OUT_D + o];
    float rs = resid_scale[i];

    unsigned short w8[NC];
    #pragma unroll
    for (int j = 0; j < NC; j++) {
        float wv = 0.f;
        #pragma unroll
        for (int c = 0; c < NC; c++) wv += mono[c][j] * cf[c];
        wv *= ss * (1.0f / IN_D);
        if (j == 1) wv += rs * (1.0f / IN_D);
        w8[j] = f2bf(wv);
    }
    uint4 pk;
    unsigned int* pu = (unsigned int*)&pk;
    #pragma unroll
    for (int h = 0; h < 4; h++)
        pu[h] = (unsigned int)w8[2 * h] | ((unsigned int)w8[2 * h + 1] << 16);
    *(uint4*)(Wg + ((size_t)i * OUT_D + o) * NC) = pk;
}

// ---------------------------------------------------------------------------
// Barrier-free GEMM, BM=128 x BN=32 (halves W L2 traffic vs R10's 64x32).
// 512 threads = 8 waves = 2 m-halves x 4 K-groups; each wave K=512, 16
// fully-unrolled steps, 64x32 output quadrant. Per step per lane: ONE
// float4 tTI load + two uint4 W loads (L2/L1-resident), power chains in
// registers, 8 MFMA. Reduce: kg>0 waves dump (55 KB LDS), kg=0 sums+stores.
// 256 blocks = 1/CU, 2 waves/SIMD.
// ---------------------------------------------------------------------------
__global__ __launch_bounds__(512) void kan_gemm(
    const float* __restrict__ tTI, const unsigned short* __restrict__ Wg,
    float* __restrict__ out)
{
    __shared__ __align__(16) float lbuf[6][64 * 36];   // 55.3 KB

    const int tid  = threadIdx.x;
    const int lane = tid & 63;
    const int wid  = tid >> 6;          // 0..7
    const int mh   = wid >> 2;          // m-half 0/1
    const int kg   = wid & 3;           // K-group 0..3
    const int lr   = lane & 15;
    const int il   = lane >> 4;         // 0..3: feature-within-step

    // XCD-aware bijective swizzle (256 % 8 == 0); 32 mblk x 8 nblk
    const int bid  = blockIdx.x;
    const int swz  = (bid & 7) * 32 + (bid >> 3);
    const int mblk = swz >> 3, nblk = swz & 7;
    const int bm = mblk * BM, bn = nblk * BN;

    f32x4 acc[4][2];
    #pragma unroll
    for (int f = 0; f < 4; f++)
        #pragma unroll
        for (int g = 0; g < 2; g++)
            acc[f][g] = (f32x4){0.f, 0.f, 0.f, 0.f};

    const float* tbase = tTI + bm + mh * 64 + lr * 4;           // + i0*B_SZ per step
    const unsigned short* wbase = Wg + ((size_t)bn + lr) * NC;  // + i0*OUT*NC

    #pragma unroll
    for (int s = 0; s < SSTEPS; ++s) {
        const int i0 = kg * 64 + s * 4 + il;     // this lane's feature index

        // W fragments: 16B/lane direct from global (L2/L1-resident)
        uint4 bw[2];
        #pragma unroll
        for (int g = 0; g < 2; g++)
            bw[g] = *(const uint4*)(wbase + ((size_t)i0 * OUT_D + g * 16) * NC);

        // t for f=0..3 in ONE float4
        f32x4 tv = *(const f32x4*)(tbase + (size_t)i0 * B_SZ);

        // A fragments: power chains in registers
        s16x8 af[4];
        #pragma unroll
        for (int f = 0; f < 4; f++) {
            float t = tv[f];
            float p2 = t * t, p3 = p2 * t, p4 = p3 * t;
            float p5 = p4 * t, p6 = p5 * t, p7 = p6 * t;
            __hip_bfloat162 h0 = __float22bfloat162_rn(make_float2(1.0f, t));
            __hip_bfloat162 h1 = __float22bfloat162_rn(make_float2(p2, p3));
            __hip_bfloat162 h2 = __float22bfloat162_rn(make_float2(p4, p5));
            __hip_bfloat162 h3 = __float22bfloat162_rn(make_float2(p6, p7));
            uint4 pk;
            pk.x = *(unsigned int*)&h0;
            pk.y = *(unsigned int*)&h1;
            pk.z = *(unsigned int*)&h2;
            pk.w = *(unsigned int*)&h3;
            af[f] = *(s16x8*)&pk;
        }

        #pragma unroll
        for (int f = 0; f < 4; f++)
            #pragma unroll
            for (int g = 0; g < 2; g++)
                acc[f][g] = __builtin_amdgcn_mfma_f32_16x16x32_bf16(
                    af[f], *(s16x8*)&bw[g], acc[f][g], 0, 0, 0);
    }

    // ---- K-split reduction: kg>0 waves dump, kg=0 waves sum + store ----
    if (kg > 0) {
        float* dst = &lbuf[mh * 3 + kg - 1][lane * 36];
        #pragma unroll
        for (int f = 0; f < 4; f++)
            #pragma unroll
            for (int g = 0; g < 2; g++)
                *(f32x4*)(dst + f * 8 + g * 4) = acc[f][g];
    }
    __syncthreads();
    if (kg == 0) {
        #pragma unroll
        for (int r = 0; r < 3; r++) {
            const float* src = &lbuf[mh * 3 + r][lane * 36];
            #pragma unroll
            for (int f = 0; f < 4; f++)
                #pragma unroll
                for (int g = 0; g < 2; g++)
                    acc[f][g] += *(const f32x4*)(src + f * 8 + g * 4);
        }
        // C/D layout: col = lane&15, row = (lane>>4)*4 + j
        #pragma unroll
        for (int f = 0; f < 4; f++)
            #pragma unroll
            for (int g = 0; g < 2; g++)
                #pragma unroll
                for (int j = 0; j < 4; j++) {
                    int r = bm + mh * 64 + f * 16 + il * 4 + j;
                    int c = bn + g * 16 + lr;
                    out[(size_t)r * OUT_D + c] = acc[f][g][j];
                }
    }
}

extern "C" void kernel_launch(void* const* d_in, const int* in_sizes, int n_in,
                              void* d_out, int out_size, void* d_ws, size_t ws_size,
                              hipStream_t stream) {
    const float* x     = (const float*)d_in[0];
    const float* coefs = (const float*)d_in[1];
    const float* alpha = (const float*)d_in[2];
    const float* rs    = (const float*)d_in[3];
    const float* ss    = (const float*)d_in[4];
    float* out = (float*)d_out;

    unsigned short* Wg = (unsigned short*)d_ws;              // 1 MB
    float* tTI = (float*)((char*)d_ws + (1 << 20));          // 4 MB

    kan_prep<<<dim3(512), dim3(256), 0, stream>>>(x, coefs, alpha, rs, ss, tTI, Wg);
    kan_gemm<<<dim3((B_SZ / BM) * (OUT_D / BN)), dim3(512), 0, stream>>>(tTI, Wg, out);
}